// Round 13
// baseline (247.016 us; speedup 1.0000x reference)
//
#include <hip/hip_runtime.h>

namespace {

constexpr int L = 10000;   // links
constexpr int F = 8;       // input features
constexpr int H = 64;      // hidden size

typedef __bf16 bf16x8 __attribute__((ext_vector_type(8)));
typedef float  f32x4  __attribute__((ext_vector_type(4)));

__device__ __forceinline__ float fsigmoid(float x) {
    return 1.0f / (1.0f + __expf(-x));
}
__device__ __forceinline__ float ftanh(float x) {
    return 2.0f / (1.0f + __expf(-2.0f * x)) - 1.0f;
}
__device__ __forceinline__ unsigned pack2(float lo, float hi) {
    __bf16 l = (__bf16)lo, h = (__bf16)hi;
    return (unsigned)__builtin_bit_cast(unsigned short, l) |
           ((unsigned)__builtin_bit_cast(unsigned short, h) << 16);
}
__device__ __forceinline__ float unbf(unsigned short u) {
    return (float)__builtin_bit_cast(__bf16, u);
}

// ---------------- workspace layout (bytes) ----------------
constexpr size_t PA_OFF  = 0;
constexpr size_t PB_OFF  = PA_OFF + (size_t)L * 4608;   //  46,080,000
constexpr size_t PNU_OFF = PB_OFF + (size_t)L * 1024;   //  56,320,000
constexpr size_t WS_NEED = PNU_OFF + (size_t)L * 8192;  // 138,240,000

// =====================================================================
// Pass 1: pack A-fragments + biases (unchanged from R12 -- at roofline).
// =====================================================================
__global__ __launch_bounds__(256)
void pre_pack(const float* __restrict__ hidden, const float* __restrict__ xin,
              const float* __restrict__ Brh, const float* __restrict__ Bri,
              const float* __restrict__ Buh, const float* __restrict__ Bui,
              const float* __restrict__ Bnh, const float* __restrict__ Bni,
              uint4* __restrict__ PA, float* __restrict__ PB)
{
    const int jt = blockIdx.x >> 2;
    const int quarter = blockIdx.x & 3;
    const int j0 = jt * 16;
    const int jl = threadIdx.x & 15;
    const int qs = threadIdx.x >> 4;
    const int j = j0 + jl;

    const int qlo = quarter * 88, qhi = qlo + 88;
    for (int q = qlo + qs; q < qhi; q += 16) {
        if (q < 256) {
            const int s = q >> 6, ql = q & 63;
            const int grp = ql >> 4, lc = ql & 15;
            const int m = s >> 1, ks = s & 1;
            const int b = m * 16 + lc;
            const int i0 = ks * 32 + grp * 8;
            const size_t base = ((size_t)b * H + i0) * L + j;
            float v[8];
#pragma unroll
            for (int e = 0; e < 8; ++e) v[e] = hidden[base + (size_t)e * L];
            uint4 w;
            w.x = pack2(v[0], v[1]); w.y = pack2(v[2], v[3]);
            w.z = pack2(v[4], v[5]); w.w = pack2(v[6], v[7]);
            PA[(size_t)j * 288 + q] = w;
        } else if (q < 288) {
            const int t = q - 256;
            const int m = t >> 4, lc = t & 15;
            const int b = m * 16 + lc;
            float v[8];
#pragma unroll
            for (int e = 0; e < 8; ++e) v[e] = xin[((size_t)b * F + e) * L + j];
            uint4 w;
            w.x = pack2(v[0], v[1]); w.y = pack2(v[2], v[3]);
            w.z = pack2(v[4], v[5]); w.w = pack2(v[6], v[7]);
            PA[(size_t)j * 288 + q] = w;
        } else {
            const int w0 = (q - 288) * 4;
            const int g = w0 >> 6, k0 = w0 & 63;
            float v[4];
#pragma unroll
            for (int e = 0; e < 4; ++e) {
                const size_t o = (size_t)(k0 + e) * L + j;
                if (g == 0)      v[e] = Brh[o] + Bri[o];
                else if (g == 1) v[e] = Buh[o] + Bui[o];
                else if (g == 2) v[e] = Bnh[o];
                else             v[e] = Bni[o];
            }
            *(f32x4*)&PB[(size_t)j * 256 + w0] = (f32x4){v[0], v[1], v[2], v[3]};
        }
    }
}

// =====================================================================
// Main: 4 links per 512-thread block (8 waves; wave = (n, m) sub-tile),
// weight LDS double-buffered. Per link: pack(k)->buf[k&1]; barrier;
// issue loads(k+1) into freed regs; compute(k). Weight stream issues
// continuously; compute hides under next link's HBM latency.
// Race safety: pack(k+1) writes buf[(k+1)&1] while stragglers read
// buf[k&1]; a wave reaches pack(k+2)->buf[k&1] only after barrier(k+1),
// which every wave passes only after its compute(k) (program order).
// =====================================================================
constexpr int WROW     = 68;
constexpr int W_GATE   = 32 * WROW;                // 2176 words
constexpr int OFF_WIN  = 3 * W_GATE;               // 6528
constexpr int WIN_GATE = 4 * WROW;                 // 272
constexpr int LDS_WORDS = OFF_WIN + 3 * WIN_GATE;  // 7344 words = 29.4 KB

struct WStage {
    f32x4 wa[3], wb[3];   // hidden-W rows (2p, 2p+1) x 3 gates
    f32x4 ia, ib;         // input-W rows (waves 0-2 only: one gate each)
    uint4 pah[2];         // A-frags (this wave's m, ks=0/1)
    uint4 pai;            // aI raw (grp0 content)
    float bi[4];          // biases for this wave's col
};

__device__ __forceinline__ void issue_loads(
    int j, int tb, const uint4* __restrict__ PA, const float* __restrict__ PB,
    const float* __restrict__ Wrh, const float* __restrict__ Wuh,
    const float* __restrict__ Wnh, const float* __restrict__ Wri,
    const float* __restrict__ Wui, const float* __restrict__ Wni,
    WStage& S)
{
    const int lane = tb & 63;
    const int w8   = tb >> 6;          // 0..7
    const int n    = w8 & 3;
    const int m    = w8 >> 2;
    const int lc   = lane & 15;
    const int col  = n * 16 + lc;

    // A-frags + bias (small, L2/L3-warm PA/PB regions)
    const uint4* pa = PA + (size_t)j * 288;
#pragma unroll
    for (int ks = 0; ks < 2; ++ks)
        S.pah[ks] = pa[(m * 2 + ks) * 64 + lane];
    S.pai = pa[256 + m * 16 + lc];
    const float* pb = PB + (size_t)j * 256;
#pragma unroll
    for (int g = 0; g < 4; ++g) S.bi[g] = pb[g * 64 + col];

    // hidden weights: thread (p = tb>>4 in 0..31, cq) loads rows 2p,2p+1 x 3 gates
    const int p  = tb >> 4;
    const int cq = (tb & 15) * 4;
    const float* WgH0 = Wrh + (size_t)j * H * H;
    const float* WgH1 = Wuh + (size_t)j * H * H;
    const float* WgH2 = Wnh + (size_t)j * H * H;
    S.wa[0] = *(const f32x4*)(WgH0 + (size_t)(2 * p) * H + cq);
    S.wb[0] = *(const f32x4*)(WgH0 + (size_t)(2 * p + 1) * H + cq);
    S.wa[1] = *(const f32x4*)(WgH1 + (size_t)(2 * p) * H + cq);
    S.wb[1] = *(const f32x4*)(WgH1 + (size_t)(2 * p + 1) * H + cq);
    S.wa[2] = *(const f32x4*)(WgH2 + (size_t)(2 * p) * H + cq);
    S.wb[2] = *(const f32x4*)(WgH2 + (size_t)(2 * p + 1) * H + cq);

    // input weights: threads 0..191 (waves 0-2, wave-uniform), one gate each
    if (tb < 192) {
        const int g  = tb >> 6;            // gate = wave id
        const int s  = tb & 63;
        const int pi = s >> 4;             // 0..3
        const int ci = (s & 15) * 4;
        const float* WgI = (g == 0 ? Wri : (g == 1 ? Wui : Wni)) + (size_t)j * F * H;
        S.ia = *(const f32x4*)(WgI + (size_t)(2 * pi) * H + ci);
        S.ib = *(const f32x4*)(WgI + (size_t)(2 * pi + 1) * H + ci);
    }
}

__device__ __forceinline__ void pack_stage(unsigned* __restrict__ sLu,
                                           const WStage& S, int tb)
{
    const int p  = tb >> 4;
    const int cq = (tb & 15) * 4;
#pragma unroll
    for (int g = 0; g < 3; ++g) {
        uint4 w;
        w.x = pack2(S.wa[g][0], S.wb[g][0]);
        w.y = pack2(S.wa[g][1], S.wb[g][1]);
        w.z = pack2(S.wa[g][2], S.wb[g][2]);
        w.w = pack2(S.wa[g][3], S.wb[g][3]);
        *(uint4*)&sLu[g * W_GATE + p * WROW + cq] = w;
    }
    if (tb < 192) {
        const int g  = tb >> 6;
        const int s  = tb & 63;
        const int pi = s >> 4;
        const int ci = (s & 15) * 4;
        uint4 w;
        w.x = pack2(S.ia[0], S.ib[0]);
        w.y = pack2(S.ia[1], S.ib[1]);
        w.z = pack2(S.ia[2], S.ib[2]);
        w.w = pack2(S.ia[3], S.ib[3]);
        *(uint4*)&sLu[OFF_WIN + g * WIN_GATE + pi * WROW + ci] = w;
    }
}

__device__ __forceinline__ void compute_store(const unsigned* __restrict__ sLu,
                                              const WStage& S, int tb, int j,
                                              uint4* __restrict__ PNU)
{
    const int lane = tb & 63;
    const int w8   = tb >> 6;
    const int n    = w8 & 3;
    const int m    = w8 >> 2;
    const int lc   = lane & 15;
    const int grp  = lane >> 4;
    const int col  = n * 16 + lc;

    const bf16x8 a0 = __builtin_bit_cast(bf16x8, S.pah[0]);
    const bf16x8 a1 = __builtin_bit_cast(bf16x8, S.pah[1]);
    const uint4 z = {0u, 0u, 0u, 0u};
    const bf16x8 ai = __builtin_bit_cast(bf16x8, (grp == 0) ? S.pai : z);

    auto rdH = [&](int g, int ks) -> bf16x8 {
        uint4 t;
        t.x = sLu[g * W_GATE + (ks * 16 + grp * 4 + 0) * WROW + col];
        t.y = sLu[g * W_GATE + (ks * 16 + grp * 4 + 1) * WROW + col];
        t.z = sLu[g * W_GATE + (ks * 16 + grp * 4 + 2) * WROW + col];
        t.w = sLu[g * W_GATE + (ks * 16 + grp * 4 + 3) * WROW + col];
        return __builtin_bit_cast(bf16x8, t);
    };
    auto rdI = [&](int g) -> bf16x8 {
        uint4 t;
        t.x = (grp == 0) ? sLu[OFF_WIN + g * WIN_GATE + 0 * WROW + col] : 0u;
        t.y = (grp == 0) ? sLu[OFF_WIN + g * WIN_GATE + 1 * WROW + col] : 0u;
        t.z = (grp == 0) ? sLu[OFF_WIN + g * WIN_GATE + 2 * WROW + col] : 0u;
        t.w = (grp == 0) ? sLu[OFF_WIN + g * WIN_GATE + 3 * WROW + col] : 0u;
        return __builtin_bit_cast(bf16x8, t);
    };

    f32x4 accR  = (f32x4){0.f, 0.f, 0.f, 0.f};
    f32x4 accU  = (f32x4){0.f, 0.f, 0.f, 0.f};
    f32x4 accN  = (f32x4){0.f, 0.f, 0.f, 0.f};
    f32x4 accNI = (f32x4){0.f, 0.f, 0.f, 0.f};

    // gate-by-gate: B-frag live range stays short (reg pressure control)
    {
        const bf16x8 f0 = rdH(0, 0), f1 = rdH(0, 1), fi = rdI(0);
        accR = __builtin_amdgcn_mfma_f32_16x16x32_bf16(a0, f0, accR, 0, 0, 0);
        accR = __builtin_amdgcn_mfma_f32_16x16x32_bf16(a1, f1, accR, 0, 0, 0);
        accR = __builtin_amdgcn_mfma_f32_16x16x32_bf16(ai, fi, accR, 0, 0, 0);
    }
    {
        const bf16x8 f0 = rdH(1, 0), f1 = rdH(1, 1), fi = rdI(1);
        accU = __builtin_amdgcn_mfma_f32_16x16x32_bf16(a0, f0, accU, 0, 0, 0);
        accU = __builtin_amdgcn_mfma_f32_16x16x32_bf16(a1, f1, accU, 0, 0, 0);
        accU = __builtin_amdgcn_mfma_f32_16x16x32_bf16(ai, fi, accU, 0, 0, 0);
    }
    {
        const bf16x8 f0 = rdH(2, 0), f1 = rdH(2, 1), fi = rdI(2);
        accN = __builtin_amdgcn_mfma_f32_16x16x32_bf16(a0, f0, accN, 0, 0, 0);
        accN = __builtin_amdgcn_mfma_f32_16x16x32_bf16(a1, f1, accN, 0, 0, 0);
        accNI = __builtin_amdgcn_mfma_f32_16x16x32_bf16(ai, fi, accNI, 0, 0, 0);
    }

    float nv4[4], uv4[4];
#pragma unroll
    for (int rr = 0; rr < 4; ++rr) {
        const float rv = fsigmoid(accR[rr] + S.bi[0]);
        uv4[rr] = fsigmoid(accU[rr] + S.bi[1]);
        nv4[rr] = ftanh(rv * (accN[rr] + S.bi[2]) + accNI[rr] + S.bi[3]);
    }
    uint4 o;
    o.x = pack2(nv4[0], nv4[1]); o.y = pack2(nv4[2], nv4[3]);
    o.z = pack2(uv4[0], uv4[1]); o.w = pack2(uv4[2], uv4[3]);
    PNU[(size_t)j * 512 + (n * 2 + m) * 64 + lane] = o;
}

__global__ __launch_bounds__(512)
void gcrnn_main(const uint4* __restrict__ PA, const float* __restrict__ PB,
                const float* __restrict__ Wrh, const float* __restrict__ Wuh,
                const float* __restrict__ Wnh, const float* __restrict__ Wri,
                const float* __restrict__ Wui, const float* __restrict__ Wni,
                uint4* __restrict__ PNU)
{
    const int j0 = blockIdx.x * 4;

    __shared__ float sL[2 * LDS_WORDS];   // 58.8 KB (double-buffered weights)
    unsigned* sLu = (unsigned*)sL;

    const int tb = threadIdx.x;

    WStage S0, S1;
    issue_loads(j0, tb, PA, PB, Wrh, Wuh, Wnh, Wri, Wui, Wni, S0);

#pragma unroll
    for (int k = 0; k < 4; ++k) {
        unsigned* buf = sLu + (k & 1) * LDS_WORDS;
        WStage& cur = (k & 1) ? S1 : S0;
        WStage& nxt = (k & 1) ? S0 : S1;

        pack_stage(buf, cur, tb);          // drains cur's loads
        __syncthreads();                   // buf[k&1] ready for all waves
        if (k < 3)
            issue_loads(j0 + k + 1, tb, PA, PB, Wrh, Wuh, Wnh, Wri, Wui, Wni, nxt);
        compute_store(buf, cur, tb, j0 + k, PNU);  // overlaps nxt loads
    }
}

// =====================================================================
// Pass 3: blend + transpose back (unchanged -- at roofline).
// =====================================================================
__global__ __launch_bounds__(256)
void post_blend(const uint4* __restrict__ PNU,
                const float* __restrict__ hidden, float* __restrict__ out)
{
    const int jt = blockIdx.x >> 2;
    const int quarter = blockIdx.x & 3;
    const int j0 = jt * 16;
    const int jl = threadIdx.x & 15;
    const int qs = threadIdx.x >> 4;
    const int j = j0 + jl;

    const int qlo = quarter * 128, qhi = qlo + 128;
    for (int q = qlo + qs; q < qhi; q += 16) {
        const int sp = q >> 6, lane = q & 63;
        const int n = sp >> 1, m = sp & 1;
        const int grp = lane >> 4, lc = lane & 15;
        const int k = n * 16 + lc;
        const int b0 = m * 16 + grp * 4;

        const uint4 pp = PNU[(size_t)j * 512 + q];
        float nn[4], u[4];
        nn[0] = unbf((unsigned short)(pp.x & 0xffff));
        nn[1] = unbf((unsigned short)(pp.x >> 16));
        nn[2] = unbf((unsigned short)(pp.y & 0xffff));
        nn[3] = unbf((unsigned short)(pp.y >> 16));
        u[0]  = unbf((unsigned short)(pp.z & 0xffff));
        u[1]  = unbf((unsigned short)(pp.z >> 16));
        u[2]  = unbf((unsigned short)(pp.w & 0xffff));
        u[3]  = unbf((unsigned short)(pp.w >> 16));
#pragma unroll
        for (int rr = 0; rr < 4; ++rr) {
            const size_t o = ((size_t)(b0 + rr) * H + k) * L + j;
            out[o] = (1.0f - u[rr]) * nn[rr] + u[rr] * hidden[o];
        }
    }
}

// =====================================================================
// Fallback (R9 kernel): used only if ws_size < WS_NEED.
// =====================================================================
constexpr int FB_OFF_XH    = LDS_WORDS;             // 7344
constexpr int FB_LDS_WORDS = FB_OFF_XH + 64 * 33;   // 9456 words

__global__ __launch_bounds__(256, 4)
void gcrnn_fallback(const float* __restrict__ hidden, const float* __restrict__ xin,
                    const float* __restrict__ Wrh, const float* __restrict__ Brh,
                    const float* __restrict__ Wri, const float* __restrict__ Bri,
                    const float* __restrict__ Wuh, const float* __restrict__ Buh,
                    const float* __restrict__ Wui, const float* __restrict__ Bui,
                    const float* __restrict__ Wnh, const float* __restrict__ Bnh,
                    const float* __restrict__ Wni, const float* __restrict__ Bni,
                    float* __restrict__ out)
{
    const int orig = blockIdx.x;
    const int j = (orig & 7) * (L / 8) + (orig >> 3);

    __shared__ float sL[FB_LDS_WORDS];
    unsigned* sLu = (unsigned*)sL;
    const int tb = threadIdx.x;

    {
        const int pr = tb >> 4;
        const int c0 = (tb & 15) * 4;
        const float* Wg[3] = {Wrh + (size_t)j * H * H, Wuh + (size_t)j * H * H,
                              Wnh + (size_t)j * H * H};
#pragma unroll
        for (int g = 0; g < 3; ++g) {
#pragma unroll
            for (int it = 0; it < 2; ++it) {
                const int p = it * 16 + pr;
                const f32x4 a = *(const f32x4*)(Wg[g] + (size_t)(2 * p) * H + c0);
                const f32x4 b = *(const f32x4*)(Wg[g] + (size_t)(2 * p + 1) * H + c0);
                uint4 w;
                w.x = pack2(a[0], b[0]); w.y = pack2(a[1], b[1]);
                w.z = pack2(a[2], b[2]); w.w = pack2(a[3], b[3]);
                *(uint4*)&sLu[g * W_GATE + p * WROW + c0] = w;
            }
        }
        if (tb < 64) {
            const int p = tb >> 4;
            const int ci = (tb & 15) * 4;
            const float* Wig[3] = {Wri + (size_t)j * F * H, Wui + (size_t)j * F * H,
                                   Wni + (size_t)j * F * H};
#pragma unroll
            for (int g = 0; g < 3; ++g) {
                const f32x4 a = *(const f32x4*)(Wig[g] + (size_t)(2 * p) * H + ci);
                const f32x4 b = *(const f32x4*)(Wig[g] + (size_t)(2 * p + 1) * H + ci);
                uint4 w;
                w.x = pack2(a[0], b[0]); w.y = pack2(a[1], b[1]);
                w.z = pack2(a[2], b[2]); w.w = pack2(a[3], b[3]);
                *(uint4*)&sLu[OFF_WIN + g * WIN_GATE + p * WROW + ci] = w;
            }
        }
#pragma unroll
        for (int it = 0; it < 8; ++it) {
            const int idx = tb + 256 * it;
            const int b = idx & 31, i = idx >> 5;
            sL[FB_OFF_XH + i * 33 + b] = hidden[(size_t)(b * H + i) * L + j];
        }
    }
    __syncthreads();

    const int lane = tb & 63;
    const int n    = tb >> 6;
    const int lc   = lane & 15;
    const int grp  = lane >> 4;
    const int col  = n * 16 + lc;

    bf16x8 aH[2][2], aI[2];
#pragma unroll
    for (int m = 0; m < 2; ++m) {
        const int b_ = m * 16 + lc;
#pragma unroll
        for (int ks = 0; ks < 2; ++ks)
#pragma unroll
            for (int e = 0; e < 8; ++e)
                aH[m][ks][e] = (__bf16)sL[FB_OFF_XH + (ks * 32 + grp * 8 + e) * 33 + b_];
        const size_t ibase = (size_t)b_ * F * L + j;
#pragma unroll
        for (int e = 0; e < 8; ++e) {
            const float v = (grp == 0) ? xin[ibase + (size_t)e * L] : 0.0f;
            aI[m][e] = (__bf16)v;
        }
    }
    __syncthreads();

    const size_t ko = (size_t)col * L + j;
    const float biR  = Brh[ko] + Bri[ko];
    const float biU  = Buh[ko] + Bui[ko];
    const float biNH = Bnh[ko];
    const float biNI = Bni[ko];

    auto rdH = [&](int g, int ks) -> bf16x8 {
        uint4 t;
        t.x = sLu[g * W_GATE + (ks * 16 + grp * 4 + 0) * WROW + col];
        t.y = sLu[g * W_GATE + (ks * 16 + grp * 4 + 1) * WROW + col];
        t.z = sLu[g * W_GATE + (ks * 16 + grp * 4 + 2) * WROW + col];
        t.w = sLu[g * W_GATE + (ks * 16 + grp * 4 + 3) * WROW + col];
        return __builtin_bit_cast(bf16x8, t);
    };
    auto rdI = [&](int g) -> bf16x8 {
        uint4 t;
        t.x = (grp == 0) ? sLu[OFF_WIN + g * WIN_GATE + 0 * WROW + col] : 0u;
        t.y = (grp == 0) ? sLu[OFF_WIN + g * WIN_GATE + 1 * WROW + col] : 0u;
        t.z = (grp == 0) ? sLu[OFF_WIN + g * WIN_GATE + 2 * WROW + col] : 0u;
        t.w = (grp == 0) ? sLu[OFF_WIN + g * WIN_GATE + 3 * WROW + col] : 0u;
        return __builtin_bit_cast(bf16x8, t);
    };

    const bf16x8 fR0 = rdH(0, 0), fR1 = rdH(0, 1);
    const bf16x8 fU0 = rdH(1, 0), fU1 = rdH(1, 1);
    const bf16x8 fN0 = rdH(2, 0), fN1 = rdH(2, 1);
    const bf16x8 fRI = rdI(0), fUI = rdI(1), fNI = rdI(2);

    f32x4 accR[2], accU[2], accN[2], accNI[2];
#pragma unroll
    for (int m = 0; m < 2; ++m) {
        accR[m]  = (f32x4){0.f, 0.f, 0.f, 0.f};
        accU[m]  = (f32x4){0.f, 0.f, 0.f, 0.f};
        accN[m]  = (f32x4){0.f, 0.f, 0.f, 0.f};
        accNI[m] = (f32x4){0.f, 0.f, 0.f, 0.f};
        accR[m] = __builtin_amdgcn_mfma_f32_16x16x32_bf16(aH[m][0], fR0, accR[m], 0, 0, 0);
        accR[m] = __builtin_amdgcn_mfma_f32_16x16x32_bf16(aH[m][1], fR1, accR[m], 0, 0, 0);
        accU[m] = __builtin_amdgcn_mfma_f32_16x16x32_bf16(aH[m][0], fU0, accU[m], 0, 0, 0);
        accU[m] = __builtin_amdgcn_mfma_f32_16x16x32_bf16(aH[m][1], fU1, accU[m], 0, 0, 0);
        accN[m] = __builtin_amdgcn_mfma_f32_16x16x32_bf16(aH[m][0], fN0, accN[m], 0, 0, 0);
        accN[m] = __builtin_amdgcn_mfma_f32_16x16x32_bf16(aH[m][1], fN1, accN[m], 0, 0, 0);
        accR[m]  = __builtin_amdgcn_mfma_f32_16x16x32_bf16(aI[m], fRI, accR[m], 0, 0, 0);
        accU[m]  = __builtin_amdgcn_mfma_f32_16x16x32_bf16(aI[m], fUI, accU[m], 0, 0, 0);
        accNI[m] = __builtin_amdgcn_mfma_f32_16x16x32_bf16(aI[m], fNI, accNI[m], 0, 0, 0);
    }

#pragma unroll
    for (int m = 0; m < 2; ++m)
#pragma unroll
        for (int rr = 0; rr < 4; ++rr) {
            const int b_ = m * 16 + grp * 4 + rr;
            const int w = FB_OFF_XH + col * 33 + b_;
            const float h = sL[w];
            const float rv = fsigmoid(accR[m][rr] + biR);
            const float uv = fsigmoid(accU[m][rr] + biU);
            const float nv = ftanh(rv * (accN[m][rr] + biNH) + accNI[m][rr] + biNI);
            sL[w] = (1.0f - uv) * nv + uv * h;
        }
    __syncthreads();

#pragma unroll
    for (int it = 0; it < 8; ++it) {
        const int idx = tb + 256 * it;
        const int b = idx & 31, k = idx >> 5;
        out[(size_t)(b * H + k) * L + j] = sL[FB_OFF_XH + k * 33 + b];
    }
}

} // namespace

extern "C" void kernel_launch(void* const* d_in, const int* in_sizes, int n_in,
                              void* d_out, int out_size, void* d_ws, size_t ws_size,
                              hipStream_t stream) {
    const float* hidden = (const float*)d_in[0];
    const float* xin    = (const float*)d_in[1];
    const float* Wrh    = (const float*)d_in[2];
    const float* Brh    = (const float*)d_in[3];
    const float* Wri    = (const float*)d_in[4];
    const float* Bri    = (const float*)d_in[5];
    const float* Wuh    = (const float*)d_in[6];
    const float* Buh    = (const float*)d_in[7];
    const float* Wui    = (const float*)d_in[8];
    const float* Bui    = (const float*)d_in[9];
    const float* Wnh    = (const float*)d_in[10];
    const float* Bnh    = (const float*)d_in[11];
    const float* Wni    = (const float*)d_in[12];
    const float* Bni    = (const float*)d_in[13];
    float* out = (float*)d_out;

    if (ws_size >= WS_NEED) {
        char* ws = (char*)d_ws;
        uint4* PA  = (uint4*)(ws + PA_OFF);
        float* PB  = (float*)(ws + PB_OFF);
        uint4* PNU = (uint4*)(ws + PNU_OFF);

        pre_pack<<<(L / 16) * 4, 256, 0, stream>>>(hidden, xin,
                                                   Brh, Bri, Buh, Bui, Bnh, Bni,
                                                   PA, PB);
        gcrnn_main<<<L / 4, 512, 0, stream>>>(PA, PB,
                                              Wrh, Wuh, Wnh, Wri, Wui, Wni,
                                              PNU);
        post_blend<<<(L / 16) * 4, 256, 0, stream>>>(PNU, hidden, out);
    } else {
        gcrnn_fallback<<<L, 256, 0, stream>>>(hidden, xin,
                                              Wrh, Brh, Wri, Bri,
                                              Wuh, Buh, Wui, Bui,
                                              Wnh, Bnh, Wni, Bni,
                                              out);
    }
}